// Round 10
// baseline (268.305 us; speedup 1.0000x reference)
//
#include <hip/hip_runtime.h>

#define NN 100000
#define NE 1600000
#define NB 782            // buckets of 128 dst nodes
#define NBPAD 1024        // padded bucket count (1 per thread in 1024-thread binfill)
#define CAPB 3072         // staging/grouped capacity per bucket (mean 2046, 22 sigma)
#define EPB 8192          // edges per binning block (196 blocks, benign atomic count)
#define BFT 1024          // binfill threads (16 waves/CU -> latency cover)
#define NBF ((NE + EPB - 1) / EPB)            // 196 binfill blocks
#define NCAST2 ((NN * 32 + 1023) / 1024)      // 3125 cast blocks (1024 thr)
#define NPREP2 16                             // prep blocks (1024 thr)
#define DPAD 136          // tile row stride (ushort)
#define OPAD 72           // O-tile row stride (ushort)
#define MAXE 64           // LDS-staged edges per node (P(deg>64) ~ 0 at mean 16)

typedef __attribute__((ext_vector_type(8))) short short8;
typedef __attribute__((ext_vector_type(4))) float f32x4;

// ---------------- helpers ----------------
__device__ __forceinline__ unsigned short bf16rn(float f) {
    unsigned u = __float_as_uint(f);
    return (unsigned short)((u + 0x7FFFu + ((u >> 16) & 1u)) >> 16);
}
__device__ __forceinline__ float4 bf2x4(uint2 g) {
    float4 r;
    r.x = __uint_as_float(g.x << 16);
    r.y = __uint_as_float(g.x & 0xFFFF0000u);
    r.z = __uint_as_float(g.y << 16);
    r.w = __uint_as_float(g.y & 0xFFFF0000u);
    return r;
}
__device__ __forceinline__ uint2 packbf4(float4 v) {
    uint2 u;
    u.x = (unsigned)bf16rn(v.x) | ((unsigned)bf16rn(v.y) << 16);
    u.y = (unsigned)bf16rn(v.z) | ((unsigned)bf16rn(v.w) << 16);
    return u;
}
// accumulate 4 bf16 features (one uint2) scaled by q
__device__ __forceinline__ void acc4(float4& a, uint2 v, float q) {
    a.x = fmaf(__uint_as_float(v.x << 16), q, a.x);
    a.y = fmaf(__uint_as_float(v.x & 0xFFFF0000u), q, a.y);
    a.z = fmaf(__uint_as_float(v.y << 16), q, a.z);
    a.w = fmaf(__uint_as_float(v.y & 0xFFFF0000u), q, a.w);
}
// decode 15-bit packed dinv[src]: exp in [112,127], 11-bit mantissa
__device__ __forceinline__ float decq(unsigned e) {
    return __uint_as_float(0x38000000u | ((e & 0x7FFFu) << 12));
}
// bijective XCD-chunk swizzle (m204)
__device__ __forceinline__ int xcd_swz(int bid, int nwg) {
    int q = nwg >> 3, r = nwg & 7;
    int x = bid & 7, j = bid >> 3;
    int base = (x < r) ? x * (q + 1) : r * (q + 1) + (x - r) * q;
    return base + j;
}

__device__ __forceinline__ int load_node(const void* ei, int i64, long long idx) {
    return i64 ? (int)((const long long*)ei)[idx] : ((const int*)ei)[idx];
}

// ---------------- fused front: binfill [0,NBF) + cast + weight prep, 1024 threads ----------------
__global__ __launch_bounds__(1024) void front_k(const void* __restrict__ ei,
                                                int* __restrict__ cur,
                                                unsigned* __restrict__ bstage,
                                                const float* __restrict__ x,
                                                ushort* __restrict__ xb,
                                                const float* __restrict__ W1,
                                                const float* __restrict__ W2,
                                                ushort* __restrict__ W1t,
                                                ushort* __restrict__ W2t) {
    __shared__ unsigned binned[EPB];      // 32 KB
    __shared__ int lcnt[NBPAD];
    __shared__ int lpos[NBPAD];
    __shared__ int gbase[NBPAD];
    __shared__ int tsum[NBPAD];
    __shared__ int i64sh;
    int bid = blockIdx.x;
    int tid = threadIdx.x;

    if (bid >= NBF) {
        int cb = bid - NBF;
        if (cb < NCAST2) {
            // ---- cast role: fp32 -> bf16 feature stream (linear [node][128]) ----
            long long i = (long long)cb * 1024 + tid;
            if (i < (long long)NN * 32)
                ((uint2*)xb)[i] = packbf4(((const float4*)x)[i]);
        } else {
            // ---- weight prep role ----
            int i = (cb - NCAST2) * 1024 + tid;
            if (i < 128 * 128) {
                int k = i >> 7, n = i & 127;
                W1t[n * 128 + k] = bf16rn(W1[k * 128 + n]);
            }
            if (i < 128 * 64) {
                int k = i >> 6, n = i & 63;
                W2t[n * 128 + k] = bf16rn(W2[k * 64 + n]);
            }
        }
        return;
    }

    // ---- binfill role (proven round-6 config: EPB=8192, 16 waves/block) ----
    long long e0 = (long long)bid * EPB;

    // inline dtype detect (wave 0)
    if (tid < 64) {
        unsigned w = ((const unsigned*)ei)[2 * tid + 1];
        unsigned long long b = __ballot(w == 0u);
        if (tid == 0) i64sh = (b == 0xFFFFFFFFFFFFFFFFull) ? 1 : 0;
    }
    lcnt[tid] = 0;
    __syncthreads();
    int i64 = i64sh;

    // pass 1: histogram destination buckets (8 edges/thread)
    for (int i = tid; i < EPB; i += BFT) {
        long long e = e0 + i;
        if (e < NE) {
            int d = load_node(ei, i64, (long long)NE + e);
            atomicAdd(&lcnt[d >> 7], 1);
        }
    }
    __syncthreads();

    // Hillis-Steele inclusive scan, 1 counter per thread
    int c = lcnt[tid];
    tsum[tid] = c;
    __syncthreads();
    for (int off = 1; off < NBPAD; off <<= 1) {
        int v = (tid >= off) ? tsum[tid - off] : 0;
        __syncthreads();
        tsum[tid] += v;
        __syncthreads();
    }
    int excl = tsum[tid] - c;
    lcnt[tid] = excl;
    lpos[tid] = excl;
    if (tid < NB) gbase[tid] = c ? atomicAdd(&cur[tid], c) : 0;
    __syncthreads();

    // pass 2: re-read (L2-hot) and scatter into binned LDS
    for (int i = tid; i < EPB; i += BFT) {
        long long e = e0 + i;
        if (e < NE) {
            int sv = load_node(ei, i64, e);
            int d  = load_node(ei, i64, (long long)NE + e);
            int b  = d >> 7;
            int p  = atomicAdd(&lpos[b], 1);
            binned[p] = ((unsigned)(d & 127) << 17) | (unsigned)sv;
        }
    }
    __syncthreads();

    // flush: one bucket per thread, contiguous runs into bucket regions
    if (tid < NB) {
        int start = lcnt[tid], endp = lpos[tid];
        int gb = gbase[tid];
        unsigned* dst = bstage + (long long)tid * CAPB;
        for (int k = start; k < endp; k++) {
            int go = gb + (k - start);
            if (go < CAPB) dst[go] = binned[k];
        }
    }
}

// ---------------- per-bucket LDS regroup -> dense CSR (plain src ints) + deg ----------------
__global__ __launch_bounds__(256) void regroup_k(const int* __restrict__ cur,
                                                 const unsigned* __restrict__ bstage,
                                                 int* __restrict__ cnt,
                                                 int* __restrict__ rowstart,
                                                 unsigned* __restrict__ grouped,
                                                 float* __restrict__ dinv) {
    __shared__ unsigned stash[CAPB];
    __shared__ unsigned srt[CAPB];
    __shared__ int lcnt[128], lofs[128], lpos[128], sc[128];
    int tid = threadIdx.x;
    int b = blockIdx.x;

    int total = cur[b];
    if (total > CAPB) total = CAPB;
    const unsigned* seg = bstage + (long long)b * CAPB;
    for (int i = tid; i < total; i += 256) stash[i] = seg[i];
    __syncthreads();

    if (tid < 128) { lcnt[tid] = 0; lpos[tid] = 0; }
    __syncthreads();
    for (int i = tid; i < total; i += 256)
        atomicAdd(&lcnt[stash[i] >> 17], 1);
    __syncthreads();

    if (tid < 128) sc[tid] = lcnt[tid];
    __syncthreads();
    for (int off = 1; off < 128; off <<= 1) {
        int v = 0;
        if (tid < 128 && tid >= off) v = sc[tid - off];
        __syncthreads();
        if (tid < 128) sc[tid] += v;
        __syncthreads();
    }
    if (tid < 128) {
        lofs[tid] = sc[tid] - lcnt[tid];
        int node = b * 128 + tid;
        if (node < NN) {
            cnt[node] = lcnt[tid];
            rowstart[node] = b * CAPB + lofs[tid];
            dinv[node] = rsqrtf((float)(lcnt[tid] + 1));   // +1: self-loop
        }
    }
    __syncthreads();

    for (int i = tid; i < total; i += 256) {
        unsigned e = stash[i];
        int nl = e >> 17;
        int p = atomicAdd(&lpos[nl], 1);
        srt[lofs[nl] + p] = e;
    }
    __syncthreads();

    unsigned* g = grouped + (long long)b * CAPB;
    for (int i = tid; i < total; i += 256) g[i] = srt[i] & 0x1FFFFu;
}

// ---------------- pack per-edge norm: src -> (src<<15) | float15(dinv[src]) ----------------
__global__ __launch_bounds__(256) void qn2_k(const int* __restrict__ cur,
                                             const float* __restrict__ dinv,
                                             unsigned* __restrict__ grouped) {
    int b = blockIdx.x;
    int total = cur[b];
    if (total > CAPB) total = CAPB;
    unsigned* g = grouped + (long long)b * CAPB;
    for (int i = threadIdx.x; i < total; i += 256) {
        unsigned s = g[i];
        unsigned bits = __float_as_uint(dinv[s]);
        g[i] = (s << 15) | ((bits >> 12) & 0x7FFFu);
    }
}

// ---------------- FUSED layer-1: CSR pull (16 nodes/block) + W1+relu+W2 on MFMA ----------------
// Gather phase == pull6 LPN=32 (proven). Then block-local 16x128 tile runs the proven
// dgemm fragment code: pack A (bf16rn, bitwise == old aggxb), 8 waves x 1 nt for W1,
// 4 waves for W2, write h2b. Eliminates the 51.2 MB aggxb round-trip + dgemm dispatch.
// NN == 6250*16 exactly -> no tail, barriers safe.
__global__ __launch_bounds__(512) void pullgemm_k(const unsigned* __restrict__ grouped,
                                                  const int* __restrict__ rowstart,
                                                  const int* __restrict__ cnt,
                                                  const float* __restrict__ dinv,
                                                  const ushort* __restrict__ hb,
                                                  const ushort* __restrict__ W1t,
                                                  const float* __restrict__ b1,
                                                  const ushort* __restrict__ W2t,
                                                  ushort* __restrict__ H2b) {
    __shared__ unsigned ed[16][MAXE];     // 4 KB
    __shared__ ushort T1[16 * DPAD];      // aggregated bf16 tile, 4.25 KB
    __shared__ ushort T2[16 * DPAD];      // post-relu tile, 4.25 KB
    __shared__ ushort Ot[16 * OPAD];      // output tile, 2.25 KB
    int tid = threadIdx.x;
    int nib = tid >> 5;
    int lane = tid & 31;
    int blk = xcd_swz(blockIdx.x, (int)gridDim.x);
    int node = blk * 16 + nib;

    const uint2* h2 = (const uint2*)hb;
    float di = dinv[node];
    float w0 = di * di;
    float4 A = make_float4(0.f, 0.f, 0.f, 0.f);
    float4 B = make_float4(0.f, 0.f, 0.f, 0.f);
    {
        float4 hv = bf2x4(h2[(unsigned)node * 32 + lane]);
        A.x = hv.x * w0; A.y = hv.y * w0; A.z = hv.z * w0; A.w = hv.w * w0;
    }

    int deg = cnt[node];
    const unsigned* row = grouped + rowstart[node];
    int s = deg < MAXE ? deg : MAXE;

    for (int t = lane; t < s; t += 32) ed[nib][t] = row[t];

    int j = 0;
    if (s >= 8) {
        uint2 v[8];
        float q[8];
#pragma unroll
        for (int t = 0; t < 8; t++) {
            unsigned e = ed[nib][t];
            q[t] = decq(e) * di;
            v[t] = h2[(e >> 15) * 32 + lane];
        }
        for (; j + 16 <= s; j += 8) {
#pragma unroll
            for (int t = 0; t < 8; t++) {
                unsigned e = ed[nib][j + 8 + t];
                uint2 nv = h2[(e >> 15) * 32 + lane];
                if (t & 1) acc4(B, v[t], q[t]);
                else       acc4(A, v[t], q[t]);
                v[t] = nv; q[t] = decq(e) * di;
            }
        }
#pragma unroll
        for (int t = 0; t < 8; t++) {
            if (t & 1) acc4(B, v[t], q[t]);
            else       acc4(A, v[t], q[t]);
        }
        j += 8;
    }
    for (; j < s; j++) {
        unsigned e = ed[nib][j];
        uint2 v0 = h2[(e >> 15) * 32 + lane];
        acc4(A, v0, decq(e) * di);
    }
    for (; j < deg; j++) {                  // overflow beyond MAXE (rare)
        unsigned e = row[j];
        uint2 v0 = h2[(e >> 15) * 32 + lane];
        acc4(A, v0, decq(e) * di);
    }

    float4 o;
    o.x = A.x + B.x; o.y = A.y + B.y; o.z = A.z + B.z; o.w = A.w + B.w;
    // pack aggregated row into LDS tile (bitwise == old aggxb contents)
    ((uint2*)T1)[nib * 34 + lane] = packbf4(o);   // 34 = DPAD*2B / 8B
    __syncthreads();

    // ---- transform phase (proven dgemm fragment code, 16-row tile) ----
    int wv = tid >> 6, l64 = tid & 63;
    int m16 = l64 & 15, quad = l64 >> 4;

    // W1 + bias + relu: wave wv computes output feats [wv*16, wv*16+16)
    f32x4 accA = (f32x4){0.f, 0.f, 0.f, 0.f};
#pragma unroll
    for (int kc = 0; kc < 4; kc++) {
        short8 aT = *(const short8*)(T1 + m16 * DPAD + kc * 32 + quad * 8);
        short8 bf = *(const short8*)(W1t + (wv * 16 + m16) * 128 + kc * 32 + quad * 8);
        accA = __builtin_amdgcn_mfma_f32_16x16x32_bf16(aT, bf, accA, 0, 0, 0);
    }
    {
        float bb = b1[wv * 16 + m16];
#pragma unroll
        for (int r = 0; r < 4; r++) {
            float v = fmaxf(accA[r] + bb, 0.f);
            T2[(quad * 4 + r) * DPAD + wv * 16 + m16] = bf16rn(v);
        }
    }
    __syncthreads();

    // W2: waves 0..3 compute output feats [wv*16, wv*16+16) of 64
    if (wv < 4) {
        f32x4 accB = (f32x4){0.f, 0.f, 0.f, 0.f};
#pragma unroll
        for (int kc = 0; kc < 4; kc++) {
            short8 aT = *(const short8*)(T2 + m16 * DPAD + kc * 32 + quad * 8);
            short8 bf = *(const short8*)(W2t + (wv * 16 + m16) * 128 + kc * 32 + quad * 8);
            accB = __builtin_amdgcn_mfma_f32_16x16x32_bf16(aT, bf, accB, 0, 0, 0);
        }
#pragma unroll
        for (int r = 0; r < 4; r++)
            Ot[(quad * 4 + r) * OPAD + wv * 16 + m16] = bf16rn(accB[r]);
    }
    __syncthreads();

    // coalesced write-out: 16 nodes x 64 bf16 = 128 uint4
    if (tid < 128) {
        int r = tid >> 3, c = tid & 7;
        ((uint4*)H2b)[(long long)(blk * 16 + r) * 8 + c] =
            *(const uint4*)(&Ot[r * OPAD + c * 8]);
    }
}

// ---------------- CSR pull (round-6 champion) for layer 2 ----------------
template <int LPN, bool BIAS, bool OUTB>
__global__ __launch_bounds__(256) void pull6_k(const unsigned* __restrict__ grouped,
                                               const int* __restrict__ rowstart,
                                               const int* __restrict__ cnt,
                                               const float* __restrict__ dinv,
                                               const ushort* __restrict__ hb,
                                               const float* __restrict__ bias,
                                               void* __restrict__ out) {
    __shared__ unsigned ed[256 / LPN][MAXE];
    int tid = threadIdx.x;
    int nib = tid / LPN;
    int lane = tid & (LPN - 1);
    int node = xcd_swz(blockIdx.x, (int)gridDim.x) * (256 / LPN) + nib;
    if (node >= NN) return;

    const uint2* h2 = (const uint2*)hb;
    float di = dinv[node];
    float w0 = di * di;
    float4 A = make_float4(0.f, 0.f, 0.f, 0.f);
    float4 B = make_float4(0.f, 0.f, 0.f, 0.f);
    {
        float4 hv = bf2x4(h2[(unsigned)node * LPN + lane]);
        A.x = hv.x * w0; A.y = hv.y * w0; A.z = hv.z * w0; A.w = hv.w * w0;
    }

    int deg = cnt[node];
    const unsigned* row = grouped + rowstart[node];
    int s = deg < MAXE ? deg : MAXE;

    for (int t = lane; t < s; t += LPN) ed[nib][t] = row[t];

    int j = 0;
    if (s >= 8) {
        uint2 v[8];
        float q[8];
#pragma unroll
        for (int t = 0; t < 8; t++) {
            unsigned e = ed[nib][t];
            q[t] = decq(e) * di;
            v[t] = h2[(e >> 15) * LPN + lane];
        }
        for (; j + 16 <= s; j += 8) {
#pragma unroll
            for (int t = 0; t < 8; t++) {
                unsigned e = ed[nib][j + 8 + t];
                uint2 nv = h2[(e >> 15) * LPN + lane];
                if (t & 1) acc4(B, v[t], q[t]);
                else       acc4(A, v[t], q[t]);
                v[t] = nv; q[t] = decq(e) * di;
            }
        }
#pragma unroll
        for (int t = 0; t < 8; t++) {
            if (t & 1) acc4(B, v[t], q[t]);
            else       acc4(A, v[t], q[t]);
        }
        j += 8;
    }
    for (; j < s; j++) {
        unsigned e = ed[nib][j];
        uint2 v0 = h2[(e >> 15) * LPN + lane];
        acc4(A, v0, decq(e) * di);
    }
    for (; j < deg; j++) {
        unsigned e = row[j];
        uint2 v0 = h2[(e >> 15) * LPN + lane];
        acc4(A, v0, decq(e) * di);
    }

    float4 o;
    o.x = A.x + B.x; o.y = A.y + B.y; o.z = A.z + B.z; o.w = A.w + B.w;
    if (BIAS) {
        float4 bb = ((const float4*)bias)[lane];
        o.x += bb.x; o.y += bb.y; o.z += bb.z; o.w += bb.w;
    }
    if (OUTB)
        ((uint2*)out)[(unsigned)node * LPN + lane] = packbf4(o);
    else
        ((float4*)out)[(unsigned)node * LPN + lane] = o;
}

// ---------------- launch ----------------
extern "C" void kernel_launch(void* const* d_in, const int* in_sizes, int n_in,
                              void* d_out, int out_size, void* d_ws, size_t ws_size,
                              hipStream_t stream) {
    const float* x  = (const float*)d_in[0];
    const void*  ei = d_in[1];
    const float* W1 = (const float*)d_in[2];
    const float* b1 = (const float*)d_in[3];
    const float* W2 = (const float*)d_in[4];
    const float* b2 = (const float*)d_in[5];
    float* out = (float*)d_out;
    char* ws = (char*)d_ws;

    int*      cur      = (int*)(ws + 0x1000);        // 3.1 KB
    int*      cnt      = (int*)(ws + 0x10000);       // 400 KB
    int*      rowstart = (int*)(ws + 0x80000);       // 400 KB
    unsigned* bstage   = (unsigned*)(ws + 0x100000); // 9.6 MB
    unsigned* grouped  = (unsigned*)(ws + 0xB00000); // 9.6 MB (packed src|dinv15)
    ushort*   xb       = (ushort*)(ws + 0x1500000);  // 25.6 MB
    ushort*   h2b      = (ushort*)(ws + 0x4800000);  // 12.8 MB
    ushort*   W1t      = (ushort*)(ws + 0x5500000);  // 32 KB
    ushort*   W2t      = (ushort*)(ws + 0x5510000);  // 16 KB
    float*    dinv     = (float*)(ws + 0x5520000);   // 400 KB

    hipMemsetAsync(cur, 0, NB * sizeof(int), stream);

    // fused front: binfill (196 blocks, dispatched first) + cast (3125) + prep (16)
    front_k<<<NBF + NCAST2 + NPREP2, BFT, 0, stream>>>(ei, cur, bstage,
                                                       x, xb, W1, W2, W1t, W2t);

    regroup_k<<<NB, 256, 0, stream>>>(cur, bstage, cnt, rowstart, grouped, dinv);
    qn2_k<<<NB, 256, 0, stream>>>(cur, dinv, grouped);

    // fused layer 1: h2b = bf16( relu((A_norm@x)@W1 + b1) @ W2 ), 16 nodes/block
    pullgemm_k<<<NN / 16, 512, 0, stream>>>(grouped, rowstart, cnt, dinv,
                                            xb, W1t, b1, W2t, h2b);

    // layer 2 aggregate: out = A_norm @ h2 + b2 (fp32 out), LPN=16 (16 nodes/block)
    pull6_k<16, true, false><<<(NN + 15) / 16, 256, 0, stream>>>(grouped, rowstart, cnt, dinv,
                                                                 h2b, b2, out);
}